// Round 2
// baseline (4970.815 us; speedup 1.0000x reference)
//
#include <hip/hip_runtime.h>
#include <math.h>

#define B_ 16
#define H_ 96
#define W_ 96
#define C_ 128
#define HW_ (H_*W_)            // 9216
#define NTOK (B_*HW_)          // 147456
#define NOUT 260

// fused conv tile geometry
#define TH 16
#define TW 32
#define B0H 28
#define B0W 44
#define B1H 26
#define B1W 42
#define B2H 22
#define B2W 38

typedef unsigned short ushort_t;
typedef unsigned int uint_t;
typedef float f32x4 __attribute__((ext_vector_type(4)));
typedef float f32x2 __attribute__((ext_vector_type(2)));
typedef short bfrag __attribute__((ext_vector_type(8)));    // 8 bf16 = 4 VGPRs (MFMA A/B frag)
typedef unsigned short us8 __attribute__((ext_vector_type(8)));

__device__ __forceinline__ float gelu_f(float t) {
    return 0.5f * t * (1.0f + erff(t * 0.7071067811865475f));
}
__device__ __forceinline__ float b2f(ushort_t u) {
    union { unsigned int i; float f; } t; t.i = (unsigned int)u << 16; return t.f;
}
__device__ __forceinline__ ushort_t f2b(float f) {
    union { float f; unsigned int i; } t; t.f = f;
    unsigned int lsb = (t.i >> 16) & 1u;
    t.i += 0x7fffu + lsb;            // round-to-nearest-even
    return (ushort_t)(t.i >> 16);
}
__device__ __forceinline__ void unp2(uint_t u, float& a, float& b) {
    union { unsigned int i; float f; } x, y;
    x.i = u << 16; y.i = u & 0xffff0000u;
    a = x.f; b = y.f;
}
__device__ __forceinline__ void unp8(const uint4 v, float* f) {
    unp2(v.x, f[0], f[1]); unp2(v.y, f[2], f[3]);
    unp2(v.z, f[4], f[5]); unp2(v.w, f[6], f[7]);
}
__device__ __forceinline__ uint_t pk2(float a, float b) {
    return (uint_t)f2b(a) | ((uint_t)f2b(b) << 16);
}
__device__ __forceinline__ uint4 pk8(const float* f) {
    uint4 v;
    v.x = pk2(f[0], f[1]); v.y = pk2(f[2], f[3]);
    v.z = pk2(f[4], f[5]); v.w = pk2(f[6], f[7]);
    return v;
}
// packed (float2) unpack of 8 bf16 channels
__device__ __forceinline__ f32x2 unp2p(uint_t u) {
    union { uint_t i; float f; } a, b;
    a.i = u << 16; b.i = u & 0xffff0000u;
    f32x2 r; r.x = a.f; r.y = b.f; return r;
}
__device__ __forceinline__ void unp8p(const uint4 v, f32x2* d) {
    d[0] = unp2p(v.x); d[1] = unp2p(v.y); d[2] = unp2p(v.z); d[3] = unp2p(v.w);
}
// load one 8-channel weight vector from LDS as 4x float2
__device__ __forceinline__ void ldw8(const float* __restrict__ w, f32x2* wv) {
    const float4 a0 = *(const float4*)w;
    const float4 a1 = *(const float4*)(w + 4);
    wv[0].x = a0.x; wv[0].y = a0.y; wv[1].x = a0.z; wv[1].y = a0.w;
    wv[2].x = a1.x; wv[2].y = a1.y; wv[3].x = a1.z; wv[3].y = a1.w;
}

// split fp32 -> bf16 hi/lo (Markidis): a ~= hi + lo, error ~2^-17 |a|
__device__ __forceinline__ void split8_to(const float* f,
                                          ushort_t* __restrict__ hdst,
                                          ushort_t* __restrict__ ldst) {
    us8 vh, vl;
    #pragma unroll
    for (int j = 0; j < 8; ++j) {
        const ushort_t h = f2b(f[j]);
        vh[j] = h;
        vl[j] = f2b(f[j] - b2f(h));
    }
    *(us8*)hdst = vh;
    *(us8*)ldst = vl;
}

// ---------------------------------------------------------------------------
// K0: pack weights into MFMA-B-fragment-native layout, transposed + split.
// pk layout: [mat][hi=0/lo=1][n(128)][k(128)] bf16;
// mat: 0 = Wf[:,0:128] (q), 1 = Wf[:,128:256] (ctx), 2 = Wh, 3 = Wp
// ---------------------------------------------------------------------------
__global__ __launch_bounds__(128) void pack_weights(
    const float* __restrict__ Wf, const float* __restrict__ Wh,
    const float* __restrict__ Wp, ushort_t* __restrict__ pk)
{
    const int n = blockIdx.x, mat = blockIdx.y, k = threadIdx.x;
    float v;
    if (mat == 0)      v = Wf[(size_t)k * NOUT + n];
    else if (mat == 1) v = Wf[(size_t)k * NOUT + C_ + n];
    else if (mat == 2) v = Wh[(size_t)k * C_ + n];
    else               v = Wp[(size_t)k * C_ + n];
    const ushort_t h = f2b(v);
    const ushort_t l = f2b(v - b2f(h));
    ushort_t* base = pk + (size_t)mat * (2 * C_ * C_);
    base[n * C_ + k] = h;
    base[C_ * C_ + n * C_ + k] = l;
}

// ---------------------------------------------------------------------------
// Per-wave split-bf16 GEMM: 64(tokens) x 32(cols at n0) x K=128.
// ---------------------------------------------------------------------------
template <bool A_LO>
__device__ __forceinline__ void mfma_gemm64(
    const ushort_t (*Ah)[136], const ushort_t (*Al)[136],
    const ushort_t* __restrict__ Bh, const ushort_t* __restrict__ Bl,
    int lane, int n0, f32x4 acc[4][2])
{
    const int ar = lane & 15;               // A row / B col within tile
    const int ak = (lane >> 4) << 3;        // k offset within 32-step
    #pragma unroll
    for (int kk = 0; kk < 4; ++kk) {
        const int kb = (kk << 5) + ak;
        const bfrag bh0 = *(const bfrag*)(Bh + (((n0      + ar) << 7) + kb));
        const bfrag bh1 = *(const bfrag*)(Bh + (((n0 + 16 + ar) << 7) + kb));
        const bfrag bl0 = *(const bfrag*)(Bl + (((n0      + ar) << 7) + kb));
        const bfrag bl1 = *(const bfrag*)(Bl + (((n0 + 16 + ar) << 7) + kb));
        #pragma unroll
        for (int m = 0; m < 4; ++m) {
            const bfrag ah = *(const bfrag*)&Ah[(m << 4) + ar][kb];
            if constexpr (A_LO) {
                const bfrag al = *(const bfrag*)&Al[(m << 4) + ar][kb];
                acc[m][0] = __builtin_amdgcn_mfma_f32_16x16x32_bf16(al, bh0, acc[m][0], 0, 0, 0);
                acc[m][1] = __builtin_amdgcn_mfma_f32_16x16x32_bf16(al, bh1, acc[m][1], 0, 0, 0);
            }
            acc[m][0] = __builtin_amdgcn_mfma_f32_16x16x32_bf16(ah, bl0, acc[m][0], 0, 0, 0);
            acc[m][1] = __builtin_amdgcn_mfma_f32_16x16x32_bf16(ah, bl1, acc[m][1], 0, 0, 0);
            acc[m][0] = __builtin_amdgcn_mfma_f32_16x16x32_bf16(ah, bh0, acc[m][0], 0, 0, 0);
            acc[m][1] = __builtin_amdgcn_mfma_f32_16x16x32_bf16(ah, bh1, acc[m][1], 0, 0, 0);
        }
    }
}

// stage 64x128 fp32 tile -> LDS bf16 hi/lo (coalesced 32B/thread reads)
__device__ __forceinline__ void stage_split_f32(
    const float* __restrict__ src, int tid,
    ushort_t (*Ah)[136], ushort_t (*Al)[136])
{
    #pragma unroll
    for (int p = 0; p < 4; ++p) {
        const int i  = tid + (p << 8);        // 0..1023
        const int t  = i >> 4;                // token row
        const int c8 = (i & 15) << 3;         // k chunk
        const float4 v0 = *(const float4*)(src + (size_t)t * C_ + c8);
        const float4 v1 = *(const float4*)(src + (size_t)t * C_ + c8 + 4);
        const float f[8] = {v0.x, v0.y, v0.z, v0.w, v1.x, v1.y, v1.z, v1.w};
        split8_to(f, &Ah[t][c8], &Al[t][c8]);
    }
}

// ---------------------------------------------------------------------------
// K1: ctx = (x @ Wf)[:, 128:256] + bf ; gates = (x @ Wf)[:, 256:260] + bf
// ---------------------------------------------------------------------------
__global__ __launch_bounds__(256) void gemm_ctx_gates_mfma(
    const float* __restrict__ x, const float* __restrict__ Wf,
    const float* __restrict__ bf, const ushort_t* __restrict__ pk,
    ushort_t* __restrict__ ctx, float* __restrict__ gates,
    float* __restrict__ csum)
{
    __shared__ ushort_t Abuf[2][64][136];     // hi / lo (34816 B)
    const int tid  = threadIdx.x;
    const int tok0 = blockIdx.x * 64;
    const int lane = tid & 63;
    const int n0   = (tid >> 6) << 5;         // wave's 32-col strip

    if (blockIdx.x < 8) csum[blockIdx.x * 256 + tid] = 0.0f;

    stage_split_f32(x + (size_t)tok0 * C_, tid, Abuf[0], Abuf[1]);
    __syncthreads();

    f32x4 acc[4][2] = {};
    {
        const ushort_t* Bh = pk + (size_t)1 * (2 * C_ * C_);   // mat 1 = Wf ctx cols
        const ushort_t* Bl = Bh + C_ * C_;
        mfma_gemm64<true>(Abuf[0], Abuf[1], Bh, Bl, lane, n0, acc);
    }

    // gates: g wave-uniform (tid>>6), token = lane; x reconstructed hi+lo from LDS
    {
        const int g = tid >> 6;
        float s = 0.f;
        #pragma unroll
        for (int k8 = 0; k8 < C_; k8 += 8) {
            const us8 vh = *(const us8*)&Abuf[0][lane][k8];
            const us8 vl = *(const us8*)&Abuf[1][lane][k8];
            #pragma unroll
            for (int j = 0; j < 8; ++j) {
                const float xv = b2f((ushort_t)vh[j]) + b2f((ushort_t)vl[j]);
                s += xv * Wf[(size_t)(k8 + j) * NOUT + 2*C_ + g];
            }
        }
        gates[(size_t)(tok0 + lane) * 4 + g] = s + bf[2*C_ + g];
    }
    __syncthreads();   // all LDS reads (frags + gates) done before overwrite

    // epilogue: acc + bias -> bf16 into Abuf[0] as ctx_lds[64][136]
    {
        const int ar = lane & 15;
        const int rg = (lane >> 4) << 2;
        #pragma unroll
        for (int n = 0; n < 2; ++n) {
            const int col = n0 + (n << 4) + ar;
            const float bias = bf[C_ + col];
            #pragma unroll
            for (int m = 0; m < 4; ++m)
                #pragma unroll
                for (int r = 0; r < 4; ++r)
                    Abuf[0][(m << 4) + rg + r][col] = f2b(acc[m][n][r] + bias);
        }
    }
    __syncthreads();

    // coalesced transposed store: ctx[colgrp][token][8]
    #pragma unroll
    for (int p = 0; p < 4; ++p) {
        const int i  = tid + (p << 8);
        const int cg = i >> 6;
        const int t  = i & 63;
        *(uint4*)(ctx + (((size_t)cg * NTOK + tok0 + t) << 3))
            = *(const uint4*)&Abuf[0][t][cg << 3];
    }
}

// ---------------------------------------------------------------------------
// conv stage helper: each thread computes P vertically-adjacent output rows
// at one column. Input read ONCE per (tap-col, input-row) and reused across
// the P outputs (vertical register reuse). Packed float2 channel math.
//   out[r][col] = sum_{a,b} in[r+a][col+b] * w[a*K+b]   (valid, halo offset)
// ---------------------------------------------------------------------------
template <int K, int P, int INW, int INH>
__device__ __forceinline__ void conv_stage(
    const uint4* __restrict__ in, const float* __restrict__ wlds,
    int col, int r0, f32x2 acc[P][4])
{
    int rbase[P + K - 1];
    #pragma unroll
    for (int rr = 0; rr < P + K - 1; ++rr) {
        int rrow = r0 + rr;
        rrow = (rrow < INH) ? rrow : (INH - 1);   // clamp: garbage only flows to masked outputs
        rbase[rr] = rrow * INW + col;
    }
    #pragma unroll
    for (int b = 0; b < K; ++b) {
        f32x2 wv[K][4];
        #pragma unroll
        for (int a = 0; a < K; ++a) ldw8(wlds + (a * K + b) * 8, wv[a]);
        #pragma unroll
        for (int rr = 0; rr < P + K - 1; ++rr) {
            f32x2 d[4]; unp8p(in[rbase[rr] + b], d);
            #pragma unroll
            for (int p = 0; p < P; ++p) {
                const int a = rr - p;
                if (a >= 0 && a < K) {
                    #pragma unroll
                    for (int c = 0; c < 4; ++c)
                        acc[p][c] = __builtin_elementwise_fma(d[c], wv[a][c], acc[p][c]);
                }
            }
        }
    }
}

// ---------------------------------------------------------------------------
// K2 (fused): conv3->gelu->conv5->gelu->conv7->gelu cascade in LDS.
// Vertical multi-pixel register reuse + packed f32x2 FMA.
// ---------------------------------------------------------------------------
__global__ __launch_bounds__(256, 4) void focal_conv_fused(
    const ushort_t* __restrict__ ctx_in,
    const float* __restrict__ k0w, const float* __restrict__ k1w,
    const float* __restrict__ k2w,
    const float* __restrict__ gates,
    ushort_t* __restrict__ ctx_all,
    float* __restrict__ csum)
{
    __shared__ uint4 bufA[B0H*B0W];            // 19712 B (stage0 in; stage2 out 22x38)
    __shared__ uint4 buf1[B1H*B1W];            // 17472 B
    __shared__ float wts[(9+25+49)*8];         //  2656 B

    const int tid  = threadIdx.x;
    const int cg   = blockIdx.x;               // 0..15 channel group
    const int tile = blockIdx.y;               // 0..17
    const int bb   = blockIdx.z;               // 0..15
    const int wt   = tile % 3, ht = tile / 3;
    const int c0   = cg << 3;
    const int h0   = ht * TH, w0 = wt * TW;

    // weights -> LDS (83 taps x 8 ch)
    if (tid < 166) {
        const int f = tid << 2;
        const float* src; int r;
        if (f < 72)       { r = f;       src = k0w; }
        else if (f < 272) { r = f - 72;  src = k1w; }
        else              { r = f - 272; src = k2w; }
        const int tap = r >> 3, off = r & 7;
        *(float4*)&wts[f] = *(const float4*)(src + tap * C_ + c0 + off);
    }

    // stage 0: global -> bufA (contiguous reads from transposed ctx)
    const ushort_t* cin = ctx_in + (((size_t)cg * NTOK + (size_t)bb * HW_) << 3);
    for (int i = tid; i < B0H*B0W; i += 256) {
        const int r = i / B0W, q = i - r * B0W;
        const int hh = h0 - 6 + r, ww = w0 - 6 + q;
        uint4 v = make_uint4(0u, 0u, 0u, 0u);
        if ((unsigned)hh < (unsigned)H_ && (unsigned)ww < (unsigned)W_)
            v = *(const uint4*)(cin + ((size_t)(hh * W_ + ww) << 3));
        bufA[i] = v;
    }
    __syncthreads();

    // ---- stage 1: buf1 = gelu(conv3(bufA))  [26x42], P=5, 252 active ----
    {
        const int c1 = tid % 42;
        const int r1 = (tid / 42) * 5;
        f32x2 acc[5][4] = {};
        conv_stage<3, 5, B0W, B0H>(bufA, wts, c1, r1, acc);
        #pragma unroll
        for (int p = 0; p < 5; ++p) {
            const int orow = r1 + p;
            if (orow < B1H) {
                float g[8];
                #pragma unroll
                for (int c = 0; c < 4; ++c) {
                    g[2*c]   = gelu_f(acc[p][c].x);
                    g[2*c+1] = gelu_f(acc[p][c].y);
                }
                buf1[orow * B1W + c1] = pk8(g);
            }
        }
    }
    __syncthreads();   // buf1 complete; all bufA(stage0) reads done

    // ---- stage 2: bufA = gelu(conv5(buf1))  [22x38], P=4, 228 active ----
    {
        const int c2 = tid % 38;
        const int r2 = (tid / 38) * 4;
        f32x2 acc[4][4] = {};
        conv_stage<5, 4, B1W, B1H>(buf1, wts + 72, c2, r2, acc);
        #pragma unroll
        for (int p = 0; p < 4; ++p) {
            const int orow = r2 + p;
            if (orow < B2H) {
                float g[8];
                #pragma unroll
                for (int c = 0; c < 4; ++c) {
                    g[2*c]   = gelu_f(acc[p][c].x);
                    g[2*c+1] = gelu_f(acc[p][c].y);
                }
                bufA[orow * B2W + c2] = pk8(g);
            }
        }
    }
    __syncthreads();   // bufA(stage2) complete before stage3 reads

    // ---- stage 3: ctx3 = gelu(conv7(bufA)); combine 3 gated levels ----
    float lsum[8] = {};
    {
        const int tw = tid & 31;
        const int r3 = (tid >> 5) << 1;        // rows r3, r3+1
        f32x2 acc[2][4] = {};
        conv_stage<7, 2, B2W, B2H>(bufA, wts + 272, tw, r3, acc);
        #pragma unroll
        for (int p = 0; p < 2; ++p) {
            const int orow = r3 + p;
            f32x2 ctx3[4];
            #pragma unroll
            for (int c = 0; c < 4; ++c) {
                ctx3[c].x = gelu_f(acc[p][c].x);
                ctx3[c].y = gelu_f(acc[p][c].y);
                lsum[2*c]   += ctx3[c].x;
                lsum[2*c+1] += ctx3[c].y;
            }
            f32x2 d1[4]; unp8p(buf1[(5 + orow) * B1W + (5 + tw)], d1);
            f32x2 d2[4]; unp8p(bufA[(orow + 3) * B2W + (tw + 3)], d2);
            const size_t pix = (size_t)bb * HW_ + (size_t)(h0 + orow) * W_ + (w0 + tw);
            const float4 gt = *(const float4*)(gates + pix * 4);
            float o[8];
            #pragma unroll
            for (int c = 0; c < 4; ++c) {
                const f32x2 ov = d1[c] * gt.x + d2[c] * gt.y + ctx3[c] * gt.z;
                o[2*c] = ov.x; o[2*c+1] = ov.y;
            }
            *(uint4*)(ctx_all + pix * C_ + c0) = pk8(o);
        }
    }

    // per-block channel sums of final ctx -> atomic accumulate
    __syncthreads();
    float* red = (float*)bufA;
    #pragma unroll
    for (int c = 0; c < 8; ++c) red[c*256 + tid] = lsum[c];
    __syncthreads();
    for (int off = 128; off > 0; off >>= 1) {
        if (tid < off) {
            #pragma unroll
            for (int c = 0; c < 8; ++c)
                red[c*256 + tid] += red[c*256 + tid + off];
        }
        __syncthreads();
    }
    if (tid < 8) atomicAdd(&csum[bb * C_ + c0 + tid], red[tid * 256]);
}

// ---------------------------------------------------------------------------
// K3: cglob = gelu(csum / HW)
// ---------------------------------------------------------------------------
__global__ __launch_bounds__(256) void mean_fin(
    const float* __restrict__ csum, float* __restrict__ cglob)
{
    const int i = blockIdx.x * 256 + threadIdx.x;
    if (i < B_ * C_) cglob[i] = gelu_f(csum[i] * (1.0f / (float)HW_));
}

// ---------------------------------------------------------------------------
// K4: mod = (ctx_all + cglob*g3) @ Wh + bh ; q = x @ Wf[:, :C] + bf[:C] ;
//     x_out = q * mod ; LayerNorm -> xln (bf16, token-major). MFMA split-bf16.
// ---------------------------------------------------------------------------
__global__ __launch_bounds__(256) void modq_ln_mfma(
    const ushort_t* __restrict__ ctx_all, const float* __restrict__ cglob,
    const float* __restrict__ gates, const float* __restrict__ x,
    const ushort_t* __restrict__ pk, const float* __restrict__ bf,
    const float* __restrict__ bh, const float* __restrict__ gamma,
    const float* __restrict__ beta, ushort_t* __restrict__ xln)
{
    __shared__ ushort_t Abuf[2][64][136];     // hi/lo staging; later aliased as xs
    __shared__ float mu_s[64];
    __shared__ float rs_s[64];
    float (*xs)[132] = (float(*)[132])&Abuf[0][0][0];   // 33792 B <= 34816 B

    const int tid  = threadIdx.x;
    const int tok0 = blockIdx.x * 64;
    const int bidx = tok0 / HW_;
    const int lane = tid & 63;
    const int n0   = (tid >> 6) << 5;

    // ---- stage A_mod = ctx_all + cglob*g3 (fp32), split hi/lo ----
    #pragma unroll
    for (int p = 0; p < 4; ++p) {
        const int i  = tid + (p << 8);
        const int t  = i >> 4;
        const int c8 = (i & 15) << 3;
        const float g3 = gates[(size_t)(tok0 + t) * 4 + 3];
        const ushort4 u0 = *(const ushort4*)(ctx_all + (size_t)(tok0 + t) * C_ + c8);
        const ushort4 u1 = *(const ushort4*)(ctx_all + (size_t)(tok0 + t) * C_ + c8 + 4);
        const float4 g0 = *(const float4*)(cglob + bidx * C_ + c8);
        const float4 g1 = *(const float4*)(cglob + bidx * C_ + c8 + 4);
        const float f[8] = {
            b2f(u0.x) + g0.x * g3, b2f(u0.y) + g0.y * g3,
            b2f(u0.z) + g0.z * g3, b2f(u0.w) + g0.w * g3,
            b2f(u1.x) + g1.x * g3, b2f(u1.y) + g1.y * g3,
            b2f(u1.z) + g1.z * g3, b2f(u1.w) + g1.w * g3 };
        split8_to(f, &Abuf[0][t][c8], &Abuf[1][t][c8]);
    }
    __syncthreads();

    f32x4 am[4][2] = {};
    {
        const ushort_t* Bh2 = pk + (size_t)2 * (2 * C_ * C_);   // mat 2 = Wh
        const ushort_t* Bl2 = Bh2 + C_ * C_;
        mfma_gemm64<true>(Abuf[0], Abuf[1], Bh2, Bl2, lane, n0, am);
    }
    __syncthreads();   // all mod-frag reads done before restaging

    // ---- stage A_q = x, split hi/lo ----
    stage_split_f32(x + (size_t)tok0 * C_, tid, Abuf[0], Abuf[1]);
    __syncthreads();

    f32x4 aq[4][2] = {};
    {
        const ushort_t* Bh0 = pk;                                // mat 0 = Wf q cols
        const ushort_t* Bl0 = Bh0 + C_ * C_;
        mfma_gemm64<true>(Abuf[0], Abuf[1], Bh0, Bl0, lane, n0, aq);
    }
    __syncthreads();   // all q-frag reads done before xs overwrites LDS

    // ---- x_out = (q + bf) * (mod + bh) -> xs ----
    {
        const int ar = lane & 15;
        const int rg = (lane >> 4) << 2;
        #pragma unroll
        for (int n = 0; n < 2; ++n) {
            const int col = n0 + (n << 4) + ar;
            const float bfv = bf[col];
            const float bhv = bh[col];
            #pragma unroll
            for (int m = 0; m < 4; ++m)
                #pragma unroll
                for (int r = 0; r < 4; ++r) {
                    const int row = (m << 4) + rg + r;
                    xs[row][col] = (aq[m][n][r] + bfv) * (am[m][n][r] + bhv);
                }
        }
    }
    __syncthreads();

    if (tid < 64) {
        float s = 0.f, s2 = 0.f;
        #pragma unroll
        for (int c = 0; c < C_; c += 4) {
            const float4 v = *(const float4*)&xs[tid][c];
            s  += v.x + v.y + v.z + v.w;
            s2 += v.x*v.x + v.y*v.y + v.z*v.z + v.w*v.w;
        }
        const float mu  = s * (1.0f / 128.0f);
        const float var = s2 * (1.0f / 128.0f) - mu * mu;
        mu_s[tid] = mu;
        rs_s[tid] = rsqrtf(var + 0.001f);
    }
    __syncthreads();

    {
        const int tt = tid >> 2;
        const int c0b = (tid & 3) << 5;
        const float mu = mu_s[tt], rs = rs_s[tt];
        ushort_t* op = xln + (size_t)(tok0 + tt) * C_;
        #pragma unroll
        for (int j = 0; j < 8; ++j) {
            const int c = c0b + (j << 2);
            const float4 v  = *(const float4*)&xs[tt][c];
            const float4 gm = *(const float4*)(gamma + c);
            const float4 bt = *(const float4*)(beta + c);
            ushort4 o;
            o.x = f2b((v.x - mu) * rs * gm.x + bt.x);
            o.y = f2b((v.y - mu) * rs * gm.y + bt.y);
            o.z = f2b((v.z - mu) * rs * gm.z + bt.z);
            o.w = f2b((v.w - mu) * rs * gm.w + bt.w);
            *(ushort4*)(op + c) = o;
        }
    }
}

// ---------------------------------------------------------------------------
// K5: out = xln @ Wp + bp. A already bf16 (no lo); B split hi/lo -> 2 MFMAs.
// ---------------------------------------------------------------------------
__global__ __launch_bounds__(256) void gemm_out_mfma(
    const ushort_t* __restrict__ xln, const ushort_t* __restrict__ pk,
    const float* __restrict__ bp, float* __restrict__ out)
{
    __shared__ ushort_t Ah[64][136];
    const int tid  = threadIdx.x;
    const int tok0 = blockIdx.x * 64;
    const int lane = tid & 63;
    const int n0   = (tid >> 6) << 5;

    #pragma unroll
    for (int p = 0; p < 4; ++p) {
        const int i  = tid + (p << 8);
        const int t  = i >> 4;
        const int c8 = (i & 15) << 3;
        *(us8*)&Ah[t][c8] = *(const us8*)(xln + (size_t)(tok0 + t) * C_ + c8);
    }
    __syncthreads();

    f32x4 acc[4][2] = {};
    {
        const ushort_t* Bh3 = pk + (size_t)3 * (2 * C_ * C_);   // mat 3 = Wp
        const ushort_t* Bl3 = Bh3 + C_ * C_;
        mfma_gemm64<false>(Ah, Ah, Bh3, Bl3, lane, n0, acc);
    }

    {
        const int ar = lane & 15;
        const int rg = (lane >> 4) << 2;
        #pragma unroll
        for (int n = 0; n < 2; ++n) {
            const int col = n0 + (n << 4) + ar;
            const float bpv = bp[col];
            #pragma unroll
            for (int m = 0; m < 4; ++m)
                #pragma unroll
                for (int r = 0; r < 4; ++r) {
                    const int row = (m << 4) + rg + r;
                    out[(size_t)(tok0 + row) * C_ + col] = acc[m][n][r] + bpv;
                }
        }
    }
}

// ---------------------------------------------------------------------------
extern "C" void kernel_launch(void* const* d_in, const int* in_sizes, int n_in,
                              void* d_out, int out_size, void* d_ws, size_t ws_size,
                              hipStream_t stream) {
    const float* x     = (const float*)d_in[0];
    const float* Wf    = (const float*)d_in[1];
    const float* bf    = (const float*)d_in[2];
    const float* Wh    = (const float*)d_in[3];
    const float* bh    = (const float*)d_in[4];
    const float* gamma = (const float*)d_in[5];
    const float* beta  = (const float*)d_in[6];
    const float* Wp    = (const float*)d_in[7];
    const float* bp    = (const float*)d_in[8];
    const float* k0    = (const float*)d_in[9];
    const float* k1    = (const float*)d_in[10];
    const float* k2    = (const float*)d_in[11];
    float* out = (float*)d_out;

    const size_t NC = (size_t)NTOK * C_;
    ushort_t* P0  = (ushort_t*)d_ws;          // ctx transposed (then reused as xln)
    ushort_t* ACC = P0 + NC;                  // ctx_all (token-major)
    float* gates  = (float*)(ACC + NC);
    float* csum   = gates + (size_t)NTOK * 4;
    float* cglob  = csum + (size_t)B_ * C_;
    ushort_t* pkw = (ushort_t*)(cglob + (size_t)B_ * C_);   // 4 mats x hi/lo x 128x128 bf16 = 256 KB

    pack_weights<<<dim3(C_, 4), 128, 0, stream>>>(Wf, Wh, Wp, pkw);
    gemm_ctx_gates_mfma<<<NTOK / 64, 256, 0, stream>>>(x, Wf, bf, pkw, P0, gates, csum);
    focal_conv_fused<<<dim3(C_/8, (H_/TH)*(W_/TW), B_), 256, 0, stream>>>(
        P0, k0, k1, k2, gates, ACC, csum);
    mean_fin<<<(B_ * C_ + 255) / 256, 256, 0, stream>>>(csum, cglob);
    modq_ln_mfma<<<NTOK / 64, 256, 0, stream>>>(ACC, cglob, gates, x, pkw, bf, bh, gamma, beta, P0);
    gemm_out_mfma<<<NTOK / 64, 256, 0, stream>>>(P0, pkw, bp, out);
}

// Round 3
// 426.605 us; speedup vs baseline: 11.6520x; 11.6520x over previous
//
#include <hip/hip_runtime.h>
#include <math.h>

#define B_ 16
#define H_ 96
#define W_ 96
#define C_ 128
#define HW_ (H_*W_)            // 9216
#define NTOK (B_*HW_)          // 147456
#define NOUT 260

// fused conv tile geometry
#define TH 16
#define TW 32
#define B0H 28
#define B0W 44
#define B1H 26
#define B1W 42
#define B2H 22
#define B2W 38

typedef unsigned short ushort_t;
typedef unsigned int uint_t;
typedef float f32x4 __attribute__((ext_vector_type(4)));
typedef float f32x2 __attribute__((ext_vector_type(2)));
typedef short bfrag __attribute__((ext_vector_type(8)));    // 8 bf16 = 4 VGPRs (MFMA A/B frag)
typedef unsigned short us8 __attribute__((ext_vector_type(8)));

__device__ __forceinline__ float gelu_f(float t) {
    return 0.5f * t * (1.0f + erff(t * 0.7071067811865475f));
}
__device__ __forceinline__ float b2f(ushort_t u) {
    union { unsigned int i; float f; } t; t.i = (unsigned int)u << 16; return t.f;
}
__device__ __forceinline__ ushort_t f2b(float f) {
    union { float f; unsigned int i; } t; t.f = f;
    unsigned int lsb = (t.i >> 16) & 1u;
    t.i += 0x7fffu + lsb;            // round-to-nearest-even
    return (ushort_t)(t.i >> 16);
}
__device__ __forceinline__ void unp2(uint_t u, float& a, float& b) {
    union { unsigned int i; float f; } x, y;
    x.i = u << 16; y.i = u & 0xffff0000u;
    a = x.f; b = y.f;
}
__device__ __forceinline__ void unp8(const uint4 v, float* f) {
    unp2(v.x, f[0], f[1]); unp2(v.y, f[2], f[3]);
    unp2(v.z, f[4], f[5]); unp2(v.w, f[6], f[7]);
}
__device__ __forceinline__ uint_t pk2(float a, float b) {
    return (uint_t)f2b(a) | ((uint_t)f2b(b) << 16);
}
__device__ __forceinline__ uint4 pk8(const float* f) {
    uint4 v;
    v.x = pk2(f[0], f[1]); v.y = pk2(f[2], f[3]);
    v.z = pk2(f[4], f[5]); v.w = pk2(f[6], f[7]);
    return v;
}
// packed (float2) unpack of 8 bf16 channels
__device__ __forceinline__ f32x2 unp2p(uint_t u) {
    union { uint_t i; float f; } a, b;
    a.i = u << 16; b.i = u & 0xffff0000u;
    f32x2 r; r.x = a.f; r.y = b.f; return r;
}
__device__ __forceinline__ void unp8p(const uint4 v, f32x2* d) {
    d[0] = unp2p(v.x); d[1] = unp2p(v.y); d[2] = unp2p(v.z); d[3] = unp2p(v.w);
}

// split fp32 -> bf16 hi/lo (Markidis): a ~= hi + lo, error ~2^-17 |a|
__device__ __forceinline__ void split8_to(const float* f,
                                          ushort_t* __restrict__ hdst,
                                          ushort_t* __restrict__ ldst) {
    us8 vh, vl;
    #pragma unroll
    for (int j = 0; j < 8; ++j) {
        const ushort_t h = f2b(f[j]);
        vh[j] = h;
        vl[j] = f2b(f[j] - b2f(h));
    }
    *(us8*)hdst = vh;
    *(us8*)ldst = vl;
}

// ---------------------------------------------------------------------------
// K0: pack weights into MFMA-B-fragment-native layout, transposed + split.
// pk layout: [mat][hi=0/lo=1][n(128)][k(128)] bf16;
// mat: 0 = Wf[:,0:128] (q), 1 = Wf[:,128:256] (ctx), 2 = Wh, 3 = Wp
// ---------------------------------------------------------------------------
__global__ __launch_bounds__(128) void pack_weights(
    const float* __restrict__ Wf, const float* __restrict__ Wh,
    const float* __restrict__ Wp, ushort_t* __restrict__ pk)
{
    const int n = blockIdx.x, mat = blockIdx.y, k = threadIdx.x;
    float v;
    if (mat == 0)      v = Wf[(size_t)k * NOUT + n];
    else if (mat == 1) v = Wf[(size_t)k * NOUT + C_ + n];
    else if (mat == 2) v = Wh[(size_t)k * C_ + n];
    else               v = Wp[(size_t)k * C_ + n];
    const ushort_t h = f2b(v);
    const ushort_t l = f2b(v - b2f(h));
    ushort_t* base = pk + (size_t)mat * (2 * C_ * C_);
    base[n * C_ + k] = h;
    base[C_ * C_ + n * C_ + k] = l;
}

// ---------------------------------------------------------------------------
// Per-wave split-bf16 GEMM: 64(tokens) x 32(cols at n0) x K=128.
// ---------------------------------------------------------------------------
template <bool A_LO>
__device__ __forceinline__ void mfma_gemm64(
    const ushort_t (*Ah)[136], const ushort_t (*Al)[136],
    const ushort_t* __restrict__ Bh, const ushort_t* __restrict__ Bl,
    int lane, int n0, f32x4 acc[4][2])
{
    const int ar = lane & 15;               // A row / B col within tile
    const int ak = (lane >> 4) << 3;        // k offset within 32-step
    #pragma unroll
    for (int kk = 0; kk < 4; ++kk) {
        const int kb = (kk << 5) + ak;
        const bfrag bh0 = *(const bfrag*)(Bh + (((n0      + ar) << 7) + kb));
        const bfrag bh1 = *(const bfrag*)(Bh + (((n0 + 16 + ar) << 7) + kb));
        const bfrag bl0 = *(const bfrag*)(Bl + (((n0      + ar) << 7) + kb));
        const bfrag bl1 = *(const bfrag*)(Bl + (((n0 + 16 + ar) << 7) + kb));
        #pragma unroll
        for (int m = 0; m < 4; ++m) {
            const bfrag ah = *(const bfrag*)&Ah[(m << 4) + ar][kb];
            if constexpr (A_LO) {
                const bfrag al = *(const bfrag*)&Al[(m << 4) + ar][kb];
                acc[m][0] = __builtin_amdgcn_mfma_f32_16x16x32_bf16(al, bh0, acc[m][0], 0, 0, 0);
                acc[m][1] = __builtin_amdgcn_mfma_f32_16x16x32_bf16(al, bh1, acc[m][1], 0, 0, 0);
            }
            acc[m][0] = __builtin_amdgcn_mfma_f32_16x16x32_bf16(ah, bl0, acc[m][0], 0, 0, 0);
            acc[m][1] = __builtin_amdgcn_mfma_f32_16x16x32_bf16(ah, bl1, acc[m][1], 0, 0, 0);
            acc[m][0] = __builtin_amdgcn_mfma_f32_16x16x32_bf16(ah, bh0, acc[m][0], 0, 0, 0);
            acc[m][1] = __builtin_amdgcn_mfma_f32_16x16x32_bf16(ah, bh1, acc[m][1], 0, 0, 0);
        }
    }
}

// stage 64x128 fp32 tile -> LDS bf16 hi/lo (coalesced 32B/thread reads)
__device__ __forceinline__ void stage_split_f32(
    const float* __restrict__ src, int tid,
    ushort_t (*Ah)[136], ushort_t (*Al)[136])
{
    #pragma unroll
    for (int p = 0; p < 4; ++p) {
        const int i  = tid + (p << 8);        // 0..1023
        const int t  = i >> 4;                // token row
        const int c8 = (i & 15) << 3;         // k chunk
        const float4 v0 = *(const float4*)(src + (size_t)t * C_ + c8);
        const float4 v1 = *(const float4*)(src + (size_t)t * C_ + c8 + 4);
        const float f[8] = {v0.x, v0.y, v0.z, v0.w, v1.x, v1.y, v1.z, v1.w};
        split8_to(f, &Ah[t][c8], &Al[t][c8]);
    }
}

// ---------------------------------------------------------------------------
// K1: ctx = (x @ Wf)[:, 128:256] + bf ; gates = (x @ Wf)[:, 256:260] + bf
// ---------------------------------------------------------------------------
__global__ __launch_bounds__(256) void gemm_ctx_gates_mfma(
    const float* __restrict__ x, const float* __restrict__ Wf,
    const float* __restrict__ bf, const ushort_t* __restrict__ pk,
    ushort_t* __restrict__ ctx, float* __restrict__ gates,
    float* __restrict__ csum)
{
    __shared__ ushort_t Abuf[2][64][136];     // hi / lo (34816 B)
    const int tid  = threadIdx.x;
    const int tok0 = blockIdx.x * 64;
    const int lane = tid & 63;
    const int n0   = (tid >> 6) << 5;         // wave's 32-col strip

    if (blockIdx.x < 8) csum[blockIdx.x * 256 + tid] = 0.0f;

    stage_split_f32(x + (size_t)tok0 * C_, tid, Abuf[0], Abuf[1]);
    __syncthreads();

    f32x4 acc[4][2] = {};
    {
        const ushort_t* Bh = pk + (size_t)1 * (2 * C_ * C_);   // mat 1 = Wf ctx cols
        const ushort_t* Bl = Bh + C_ * C_;
        mfma_gemm64<true>(Abuf[0], Abuf[1], Bh, Bl, lane, n0, acc);
    }

    // gates: g wave-uniform (tid>>6), token = lane; x reconstructed hi+lo from LDS
    {
        const int g = tid >> 6;
        float s = 0.f;
        #pragma unroll
        for (int k8 = 0; k8 < C_; k8 += 8) {
            const us8 vh = *(const us8*)&Abuf[0][lane][k8];
            const us8 vl = *(const us8*)&Abuf[1][lane][k8];
            #pragma unroll
            for (int j = 0; j < 8; ++j) {
                const float xv = b2f((ushort_t)vh[j]) + b2f((ushort_t)vl[j]);
                s += xv * Wf[(size_t)(k8 + j) * NOUT + 2*C_ + g];
            }
        }
        gates[(size_t)(tok0 + lane) * 4 + g] = s + bf[2*C_ + g];
    }
    __syncthreads();   // all LDS reads (frags + gates) done before overwrite

    // epilogue: acc + bias -> bf16 into Abuf[0] as ctx_lds[64][136]
    {
        const int ar = lane & 15;
        const int rg = (lane >> 4) << 2;
        #pragma unroll
        for (int n = 0; n < 2; ++n) {
            const int col = n0 + (n << 4) + ar;
            const float bias = bf[C_ + col];
            #pragma unroll
            for (int m = 0; m < 4; ++m)
                #pragma unroll
                for (int r = 0; r < 4; ++r)
                    Abuf[0][(m << 4) + rg + r][col] = f2b(acc[m][n][r] + bias);
        }
    }
    __syncthreads();

    // coalesced transposed store: ctx[colgrp][token][8]
    #pragma unroll
    for (int p = 0; p < 4; ++p) {
        const int i  = tid + (p << 8);
        const int cg = i >> 6;
        const int t  = i & 63;
        *(uint4*)(ctx + (((size_t)cg * NTOK + tok0 + t) << 3))
            = *(const uint4*)&Abuf[0][t][cg << 3];
    }
}

// ---------------------------------------------------------------------------
// K2 (fused): conv3->gelu->conv5->gelu->conv7->gelu cascade in LDS.
// Round-1 proven structure (tap-outer, no weight-column preload, no helper fn);
// only change: channel math in packed f32x2 (v_pk_fma_f32), 4 FMA instead of 8.
// ---------------------------------------------------------------------------
__global__ __launch_bounds__(256, 4) void focal_conv_fused(
    const ushort_t* __restrict__ ctx_in,
    const float* __restrict__ k0w, const float* __restrict__ k1w,
    const float* __restrict__ k2w,
    const float* __restrict__ gates,
    ushort_t* __restrict__ ctx_all,
    float* __restrict__ csum)
{
    __shared__ uint4 bufA[B0H*B0W];            // 19712 B (stage0 in; stage2 out 22x38)
    __shared__ uint4 buf1[B1H*B1W];            // 17472 B
    __shared__ float wts[(9+25+49)*8];         //  2656 B   (39840 total)

    const int tid  = threadIdx.x;
    const int cg   = blockIdx.x;               // 0..15 channel group
    const int tile = blockIdx.y;               // 0..17
    const int bb   = blockIdx.z;               // 0..15
    const int wt   = tile % 3, ht = tile / 3;
    const int c0   = cg << 3;
    const int h0   = ht * TH, w0 = wt * TW;

    // weights -> LDS (83 taps x 8 ch)
    if (tid < 166) {
        const int f = tid << 2;
        const float* src; int r;
        if (f < 72)       { r = f;       src = k0w; }
        else if (f < 272) { r = f - 72;  src = k1w; }
        else              { r = f - 272; src = k2w; }
        const int tap = r >> 3, off = r & 7;
        *(float4*)&wts[f] = *(const float4*)(src + tap * C_ + c0 + off);
    }

    // stage 0: global -> bufA (contiguous reads from transposed ctx)
    const ushort_t* cin = ctx_in + (((size_t)cg * NTOK + (size_t)bb * HW_) << 3);
    for (int i = tid; i < B0H*B0W; i += 256) {
        const int r = i / B0W, q = i - r * B0W;
        const int hh = h0 - 6 + r, ww = w0 - 6 + q;
        uint4 v = make_uint4(0u, 0u, 0u, 0u);
        if ((unsigned)hh < (unsigned)H_ && (unsigned)ww < (unsigned)W_)
            v = *(const uint4*)(cin + ((size_t)(hh * W_ + ww) << 3));
        bufA[i] = v;
    }
    __syncthreads();

    // ---- stage 1: buf1 = gelu(conv3(bufA))  [26x42] ----
    {
        int iv[5], ecp[5], boff[5];
        #pragma unroll
        for (int p = 0; p < 5; ++p) {
            const int e = tid + (p << 8);
            iv[p] = (e < B1H*B1W);
            const int ec = iv[p] ? e : 0;
            ecp[p] = ec;
            boff[p] = (ec / B1W) * B0W + (ec % B1W);
        }
        f32x2 acc[5][4] = {};
        #pragma unroll 1
        for (int a = 0; a < 3; ++a) {
            #pragma unroll
            for (int b = 0; b < 3; ++b) {
                f32x2 wv[4];
                #pragma unroll
                for (int c = 0; c < 4; ++c)
                    wv[c] = *(const f32x2*)&wts[(a*3+b)*8 + 2*c];
                const int off = a * B0W + b;
                #pragma unroll
                for (int p = 0; p < 5; ++p) {
                    f32x2 d[4]; unp8p(bufA[boff[p] + off], d);
                    #pragma unroll
                    for (int c = 0; c < 4; ++c)
                        acc[p][c] = __builtin_elementwise_fma(d[c], wv[c], acc[p][c]);
                }
            }
        }
        __syncthreads();   // all bufA reads done before stage2 overwrites it
        #pragma unroll
        for (int p = 0; p < 5; ++p) if (iv[p]) {
            float g[8];
            #pragma unroll
            for (int c = 0; c < 4; ++c) {
                g[2*c]   = gelu_f(acc[p][c].x);
                g[2*c+1] = gelu_f(acc[p][c].y);
            }
            buf1[ecp[p]] = pk8(g);
        }
    }
    __syncthreads();

    // ---- stage 2: bufA = gelu(conv5(buf1))  [22x38] ----
    {
        int iv[4], ecp[4], boff[4];
        #pragma unroll
        for (int p = 0; p < 4; ++p) {
            const int e = tid + (p << 8);
            iv[p] = (e < B2H*B2W);
            const int ec = iv[p] ? e : 0;
            ecp[p] = ec;
            boff[p] = (ec / B2W) * B1W + (ec % B2W);
        }
        f32x2 acc[4][4] = {};
        #pragma unroll 1
        for (int a = 0; a < 5; ++a) {
            #pragma unroll
            for (int b = 0; b < 5; ++b) {
                f32x2 wv[4];
                #pragma unroll
                for (int c = 0; c < 4; ++c)
                    wv[c] = *(const f32x2*)&wts[72 + (a*5+b)*8 + 2*c];
                const int off = a * B1W + b;
                #pragma unroll
                for (int p = 0; p < 4; ++p) {
                    f32x2 d[4]; unp8p(buf1[boff[p] + off], d);
                    #pragma unroll
                    for (int c = 0; c < 4; ++c)
                        acc[p][c] = __builtin_elementwise_fma(d[c], wv[c], acc[p][c]);
                }
            }
        }
        __syncthreads();   // bufA stage-0 data fully dead (stage1 done) — safe to overwrite
        #pragma unroll
        for (int p = 0; p < 4; ++p) if (iv[p]) {
            float g[8];
            #pragma unroll
            for (int c = 0; c < 4; ++c) {
                g[2*c]   = gelu_f(acc[p][c].x);
                g[2*c+1] = gelu_f(acc[p][c].y);
            }
            bufA[ecp[p]] = pk8(g);
        }
    }
    __syncthreads();

    // ---- stage 3: ctx3 = gelu(conv7(bufA)); combine 3 gated levels ----
    float lsum[8] = {};
    {
        const int th0 = tid >> 5, tw0 = tid & 31;   // p adds 8 to th
        f32x2 acc[2][4] = {};
        #pragma unroll 1
        for (int a = 0; a < 7; ++a) {
            #pragma unroll
            for (int b = 0; b < 7; ++b) {
                f32x2 wv[4];
                #pragma unroll
                for (int c = 0; c < 4; ++c)
                    wv[c] = *(const f32x2*)&wts[272 + (a*7+b)*8 + 2*c];
                #pragma unroll
                for (int p = 0; p < 2; ++p) {
                    const int th = th0 + (p << 3);
                    f32x2 d[4]; unp8p(bufA[(th + a)*B2W + (tw0 + b)], d);
                    #pragma unroll
                    for (int c = 0; c < 4; ++c)
                        acc[p][c] = __builtin_elementwise_fma(d[c], wv[c], acc[p][c]);
                }
            }
        }
        #pragma unroll
        for (int p = 0; p < 2; ++p) {
            const int th = th0 + (p << 3);
            float ctx3[8];
            #pragma unroll
            for (int c = 0; c < 4; ++c) {
                ctx3[2*c]   = gelu_f(acc[p][c].x);
                ctx3[2*c+1] = gelu_f(acc[p][c].y);
            }
            #pragma unroll
            for (int c = 0; c < 8; ++c) lsum[c] += ctx3[c];
            float d1[8]; unp8(buf1[(5+th)*B1W + (5+tw0)], d1);
            float d2[8]; unp8(bufA[(th+3)*B2W + (tw0+3)], d2);
            const size_t pix = (size_t)bb * HW_ + (size_t)(h0 + th) * W_ + (w0 + tw0);
            const float4 gt = *(const float4*)(gates + pix * 4);
            float o[8];
            #pragma unroll
            for (int c = 0; c < 8; ++c)
                o[c] = d1[c] * gt.x + d2[c] * gt.y + ctx3[c] * gt.z;
            *(uint4*)(ctx_all + pix * C_ + c0) = pk8(o);
        }
    }

    // per-block channel sums of final ctx -> atomic accumulate
    __syncthreads();
    float* red = (float*)bufA;
    #pragma unroll
    for (int c = 0; c < 8; ++c) red[c*256 + tid] = lsum[c];
    __syncthreads();
    for (int off = 128; off > 0; off >>= 1) {
        if (tid < off) {
            #pragma unroll
            for (int c = 0; c < 8; ++c)
                red[c*256 + tid] += red[c*256 + tid + off];
        }
        __syncthreads();
    }
    if (tid < 8) atomicAdd(&csum[bb * C_ + c0 + tid], red[tid * 256]);
}

// ---------------------------------------------------------------------------
// K3: cglob = gelu(csum / HW)
// ---------------------------------------------------------------------------
__global__ __launch_bounds__(256) void mean_fin(
    const float* __restrict__ csum, float* __restrict__ cglob)
{
    const int i = blockIdx.x * 256 + threadIdx.x;
    if (i < B_ * C_) cglob[i] = gelu_f(csum[i] * (1.0f / (float)HW_));
}

// ---------------------------------------------------------------------------
// K4: mod = (ctx_all + cglob*g3) @ Wh + bh ; q = x @ Wf[:, :C] + bf[:C] ;
//     x_out = q * mod ; LayerNorm -> xln (bf16, token-major). MFMA split-bf16.
// ---------------------------------------------------------------------------
__global__ __launch_bounds__(256) void modq_ln_mfma(
    const ushort_t* __restrict__ ctx_all, const float* __restrict__ cglob,
    const float* __restrict__ gates, const float* __restrict__ x,
    const ushort_t* __restrict__ pk, const float* __restrict__ bf,
    const float* __restrict__ bh, const float* __restrict__ gamma,
    const float* __restrict__ beta, ushort_t* __restrict__ xln)
{
    __shared__ ushort_t Abuf[2][64][136];     // hi/lo staging; later aliased as xs
    __shared__ float mu_s[64];
    __shared__ float rs_s[64];
    float (*xs)[132] = (float(*)[132])&Abuf[0][0][0];   // 33792 B <= 34816 B

    const int tid  = threadIdx.x;
    const int tok0 = blockIdx.x * 64;
    const int bidx = tok0 / HW_;
    const int lane = tid & 63;
    const int n0   = (tid >> 6) << 5;

    // ---- stage A_mod = ctx_all + cglob*g3 (fp32), split hi/lo ----
    #pragma unroll
    for (int p = 0; p < 4; ++p) {
        const int i  = tid + (p << 8);
        const int t  = i >> 4;
        const int c8 = (i & 15) << 3;
        const float g3 = gates[(size_t)(tok0 + t) * 4 + 3];
        const ushort4 u0 = *(const ushort4*)(ctx_all + (size_t)(tok0 + t) * C_ + c8);
        const ushort4 u1 = *(const ushort4*)(ctx_all + (size_t)(tok0 + t) * C_ + c8 + 4);
        const float4 g0 = *(const float4*)(cglob + bidx * C_ + c8);
        const float4 g1 = *(const float4*)(cglob + bidx * C_ + c8 + 4);
        const float f[8] = {
            b2f(u0.x) + g0.x * g3, b2f(u0.y) + g0.y * g3,
            b2f(u0.z) + g0.z * g3, b2f(u0.w) + g0.w * g3,
            b2f(u1.x) + g1.x * g3, b2f(u1.y) + g1.y * g3,
            b2f(u1.z) + g1.z * g3, b2f(u1.w) + g1.w * g3 };
        split8_to(f, &Abuf[0][t][c8], &Abuf[1][t][c8]);
    }
    __syncthreads();

    f32x4 am[4][2] = {};
    {
        const ushort_t* Bh2 = pk + (size_t)2 * (2 * C_ * C_);   // mat 2 = Wh
        const ushort_t* Bl2 = Bh2 + C_ * C_;
        mfma_gemm64<true>(Abuf[0], Abuf[1], Bh2, Bl2, lane, n0, am);
    }
    __syncthreads();   // all mod-frag reads done before restaging

    // ---- stage A_q = x, split hi/lo ----
    stage_split_f32(x + (size_t)tok0 * C_, tid, Abuf[0], Abuf[1]);
    __syncthreads();

    f32x4 aq[4][2] = {};
    {
        const ushort_t* Bh0 = pk;                                // mat 0 = Wf q cols
        const ushort_t* Bl0 = Bh0 + C_ * C_;
        mfma_gemm64<true>(Abuf[0], Abuf[1], Bh0, Bl0, lane, n0, aq);
    }
    __syncthreads();   // all q-frag reads done before xs overwrites LDS

    // ---- x_out = (q + bf) * (mod + bh) -> xs ----
    {
        const int ar = lane & 15;
        const int rg = (lane >> 4) << 2;
        #pragma unroll
        for (int n = 0; n < 2; ++n) {
            const int col = n0 + (n << 4) + ar;
            const float bfv = bf[col];
            const float bhv = bh[col];
            #pragma unroll
            for (int m = 0; m < 4; ++m)
                #pragma unroll
                for (int r = 0; r < 4; ++r) {
                    const int row = (m << 4) + rg + r;
                    xs[row][col] = (aq[m][n][r] + bfv) * (am[m][n][r] + bhv);
                }
        }
    }
    __syncthreads();

    if (tid < 64) {
        float s = 0.f, s2 = 0.f;
        #pragma unroll
        for (int c = 0; c < C_; c += 4) {
            const float4 v = *(const float4*)&xs[tid][c];
            s  += v.x + v.y + v.z + v.w;
            s2 += v.x*v.x + v.y*v.y + v.z*v.z + v.w*v.w;
        }
        const float mu  = s * (1.0f / 128.0f);
        const float var = s2 * (1.0f / 128.0f) - mu * mu;
        mu_s[tid] = mu;
        rs_s[tid] = rsqrtf(var + 0.001f);
    }
    __syncthreads();

    {
        const int tt = tid >> 2;
        const int c0b = (tid & 3) << 5;
        const float mu = mu_s[tt], rs = rs_s[tt];
        ushort_t* op = xln + (size_t)(tok0 + tt) * C_;
        #pragma unroll
        for (int j = 0; j < 8; ++j) {
            const int c = c0b + (j << 2);
            const float4 v  = *(const float4*)&xs[tt][c];
            const float4 gm = *(const float4*)(gamma + c);
            const float4 bt = *(const float4*)(beta + c);
            ushort4 o;
            o.x = f2b((v.x - mu) * rs * gm.x + bt.x);
            o.y = f2b((v.y - mu) * rs * gm.y + bt.y);
            o.z = f2b((v.z - mu) * rs * gm.z + bt.z);
            o.w = f2b((v.w - mu) * rs * gm.w + bt.w);
            *(ushort4*)(op + c) = o;
        }
    }
}

// ---------------------------------------------------------------------------
// K5: out = xln @ Wp + bp. A already bf16 (no lo); B split hi/lo -> 2 MFMAs.
// ---------------------------------------------------------------------------
__global__ __launch_bounds__(256) void gemm_out_mfma(
    const ushort_t* __restrict__ xln, const ushort_t* __restrict__ pk,
    const float* __restrict__ bp, float* __restrict__ out)
{
    __shared__ ushort_t Ah[64][136];
    const int tid  = threadIdx.x;
    const int tok0 = blockIdx.x * 64;
    const int lane = tid & 63;
    const int n0   = (tid >> 6) << 5;

    #pragma unroll
    for (int p = 0; p < 4; ++p) {
        const int i  = tid + (p << 8);
        const int t  = i >> 4;
        const int c8 = (i & 15) << 3;
        *(us8*)&Ah[t][c8] = *(const us8*)(xln + (size_t)(tok0 + t) * C_ + c8);
    }
    __syncthreads();

    f32x4 acc[4][2] = {};
    {
        const ushort_t* Bh3 = pk + (size_t)3 * (2 * C_ * C_);   // mat 3 = Wp
        const ushort_t* Bl3 = Bh3 + C_ * C_;
        mfma_gemm64<false>(Ah, Ah, Bh3, Bl3, lane, n0, acc);
    }

    {
        const int ar = lane & 15;
        const int rg = (lane >> 4) << 2;
        #pragma unroll
        for (int n = 0; n < 2; ++n) {
            const int col = n0 + (n << 4) + ar;
            const float bpv = bp[col];
            #pragma unroll
            for (int m = 0; m < 4; ++m)
                #pragma unroll
                for (int r = 0; r < 4; ++r) {
                    const int row = (m << 4) + rg + r;
                    out[(size_t)(tok0 + row) * C_ + col] = acc[m][n][r] + bpv;
                }
        }
    }
}

// ---------------------------------------------------------------------------
extern "C" void kernel_launch(void* const* d_in, const int* in_sizes, int n_in,
                              void* d_out, int out_size, void* d_ws, size_t ws_size,
                              hipStream_t stream) {
    const float* x     = (const float*)d_in[0];
    const float* Wf    = (const float*)d_in[1];
    const float* bf    = (const float*)d_in[2];
    const float* Wh    = (const float*)d_in[3];
    const float* bh    = (const float*)d_in[4];
    const float* gamma = (const float*)d_in[5];
    const float* beta  = (const float*)d_in[6];
    const float* Wp    = (const float*)d_in[7];
    const float* bp    = (const float*)d_in[8];
    const float* k0    = (const float*)d_in[9];
    const float* k1    = (const float*)d_in[10];
    const float* k2    = (const float*)d_in[11];
    float* out = (float*)d_out;

    const size_t NC = (size_t)NTOK * C_;
    ushort_t* P0  = (ushort_t*)d_ws;          // ctx transposed (then reused as xln)
    ushort_t* ACC = P0 + NC;                  // ctx_all (token-major)
    float* gates  = (float*)(ACC + NC);
    float* csum   = gates + (size_t)NTOK * 4;
    float* cglob  = csum + (size_t)B_ * C_;
    ushort_t* pkw = (ushort_t*)(cglob + (size_t)B_ * C_);   // 4 mats x hi/lo x 128x128 bf16 = 256 KB

    pack_weights<<<dim3(C_, 4), 128, 0, stream>>>(Wf, Wh, Wp, pkw);
    gemm_ctx_gates_mfma<<<NTOK / 64, 256, 0, stream>>>(x, Wf, bf, pkw, P0, gates, csum);
    focal_conv_fused<<<dim3(C_/8, (H_/TH)*(W_/TW), B_), 256, 0, stream>>>(
        P0, k0, k1, k2, gates, ACC, csum);
    mean_fin<<<(B_ * C_ + 255) / 256, 256, 0, stream>>>(csum, cglob);
    modq_ln_mfma<<<NTOK / 64, 256, 0, stream>>>(ACC, cglob, gates, x, pkw, bf, bh, gamma, beta, P0);
    gemm_out_mfma<<<NTOK / 64, 256, 0, stream>>>(P0, pkw, bp, out);
}